// Round 8
// baseline (2042.438 us; speedup 1.0000x reference)
//
#include <hip/hip_runtime.h>

// Problem constants (fixed by reference).
constexpr int NNODES = 200000;
constexpr int NAUT   = 100000;
constexpr int NEDGE  = 600000;
constexpr int HIDC   = 128;
constexpr int OUTCH  = 64;
constexpr int RELS   = 4;
constexpr int SCAN_N = RELS * NNODES;  // 800000 bins
constexpr int LDAF   = 140;            // fp32 LDS row stride (560B: 16B-aligned, bank stride 3)

typedef __attribute__((ext_vector_type(8))) short bf16x8;
typedef __attribute__((ext_vector_type(4))) float f32x4;

// ---------------- bf16 split helpers ----------------
__device__ __forceinline__ unsigned short f2bf(float f) {
    unsigned int b = __float_as_uint(f);
    b += 0x7FFFu + ((b >> 16) & 1u);  // round-to-nearest-even
    return (unsigned short)(b >> 16);
}
__device__ __forceinline__ float bf2f(unsigned short u) {
    return __uint_as_float(((unsigned int)u) << 16);
}

// MFMA B/A fragment offset for element (k,n) of a [128 x N] matrix, NB = N/16.
// Layout: [kb][nb][lane][j] with lane = ((k>>3)&3)*16 + (n&15), j = k&7.
__device__ __forceinline__ int fragoff(int k, int n, int NB) {
    return ((k >> 5) * NB + (n >> 4)) * 512 + (((k >> 3) & 3) * 16 + (n & 15)) * 8 + (k & 7);
}

// ---------------- prep kernels ----------------

// int count per (relation, dst) bin
__global__ void count_kernel(const int* __restrict__ dst, const int* __restrict__ et,
                             int* __restrict__ bins) {
    int e = blockIdx.x * 256 + threadIdx.x;
    if (e < NEDGE) atomicAdd(&bins[et[e] * NNODES + dst[e]], 1);
}

// ---- deterministic 3-phase exclusive scan (counts -> starts), in-place ----
// Global ordering is REQUIRED: the conv gather assumes the 64 bins of a
// (relation, dst-block) occupy one contiguous ascending srcSorted range.
__global__ void scan1_kernel(int* __restrict__ bins, int* __restrict__ blockSums) {
    __shared__ int s[256];
    int b = blockIdx.x, t = threadIdx.x;
    int base = b * 1024 + t * 4;
    int v[4], sum = 0;
#pragma unroll
    for (int i = 0; i < 4; i++) {
        v[i] = (base + i < SCAN_N) ? bins[base + i] : 0;
        sum += v[i];
    }
    s[t] = sum;
    __syncthreads();
    for (int off = 1; off < 256; off <<= 1) {
        int x = (t >= off) ? s[t - off] : 0;
        __syncthreads();
        if (t >= off) s[t] += x;
        __syncthreads();
    }
    int run = s[t] - sum;
    if (t == 255) blockSums[b] = s[255];
#pragma unroll
    for (int i = 0; i < 4; i++) {
        if (base + i < SCAN_N) bins[base + i] = run;
        run += v[i];
    }
}

__global__ void scan2_kernel(int* __restrict__ blockSums, int nb) {
    __shared__ int s[256];
    int t = threadIdx.x;
    int carry = 0;
    for (int base = 0; base < nb; base += 256) {
        int v = (base + t < nb) ? blockSums[base + t] : 0;
        s[t] = v;
        __syncthreads();
        for (int off = 1; off < 256; off <<= 1) {
            int x = (t >= off) ? s[t - off] : 0;
            __syncthreads();
            if (t >= off) s[t] += x;
            __syncthreads();
        }
        if (base + t < nb) blockSums[base + t] = carry + (s[t] - v);
        int total = s[255];
        __syncthreads();
        carry += total;
    }
}

__global__ void scan3_kernel(int* __restrict__ bins, const int* __restrict__ blockSums,
                             int* __restrict__ binCur) {
    int i = blockIdx.x * 256 + threadIdx.x;
    if (i < SCAN_N) {
        int v = bins[i] + blockSums[i >> 10];
        bins[i] = v;
        binCur[i] = v;
    }
}

// scatter packed (row<<18 | src) into (relation,dst)-sorted order.
// src < 2^18; row = dst & 63 (dst-blocks are 64-aligned). binCur -> end offsets.
__global__ void scatter_kernel(const int* __restrict__ src, const int* __restrict__ dst,
                               const int* __restrict__ et, int* __restrict__ binCur,
                               int* __restrict__ srcSorted) {
    int e = blockIdx.x * 256 + threadIdx.x;
    if (e < NEDGE) {
        int d = dst[e];
        int bin = et[e] * NNODES + d;
        int pos = atomicAdd(&binCur[bin], 1);
        srcSorted[pos] = src[e] | ((d & 63) << 18);
    }
}

// Build all relation/root weights directly into MFMA B-fragment layout,
// split into bf16 hi/lo pairs. One thread per matrix element.
__global__ void fragify_kernel(const float* __restrict__ basis0, const float* __restrict__ comp0,
                               const float* __restrict__ basis1, const float* __restrict__ comp1,
                               const float* __restrict__ root1,
                               const float* __restrict__ basis2, const float* __restrict__ comp2,
                               const float* __restrict__ root2,
                               short* __restrict__ whi0, short* __restrict__ wlo0,
                               short* __restrict__ whi1, short* __restrict__ wlo1,
                               short* __restrict__ whiR1, short* __restrict__ wloR1,
                               short* __restrict__ whi2, short* __restrict__ wlo2,
                               short* __restrict__ whiR2, short* __restrict__ wloR2) {
    int idx = blockIdx.x * 256 + threadIdx.x;
    if (idx >= 188416) return;
    float w;
    short *hp, *lp;
    if (idx < 65536) {
        int r = idx >> 14, e = idx & 16383;
        int k = e >> 7, n = e & 127;
        w = 0.f;
#pragma unroll
        for (int b = 0; b < 4; b++) w += comp0[r * 4 + b] * basis0[b * 16384 + e];
        int off = r * 16384 + fragoff(k, n, 8);
        hp = whi0 + off; lp = wlo0 + off;
    } else if (idx < 131072) {
        int i2 = idx - 65536;
        int r = i2 >> 14, e = i2 & 16383;
        int k = e >> 7, n = e & 127;
        w = 0.f;
#pragma unroll
        for (int b = 0; b < 4; b++) w += comp1[r * 4 + b] * basis1[b * 16384 + e];
        int off = r * 16384 + fragoff(k, n, 8);
        hp = whi1 + off; lp = wlo1 + off;
    } else if (idx < 147456) {
        int e = idx - 131072;
        int k = e >> 7, n = e & 127;
        w = root1[e];
        int off = fragoff(k, n, 8);
        hp = whiR1 + off; lp = wloR1 + off;
    } else if (idx < 180224) {
        int i2 = idx - 147456;
        int r = i2 >> 13, e = i2 & 8191;
        int k = e >> 6, n = e & 63;
        w = 0.f;
#pragma unroll
        for (int b = 0; b < 4; b++) w += comp2[r * 4 + b] * basis2[b * 8192 + e];
        int off = r * 8192 + fragoff(k, n, 4);
        hp = whi2 + off; lp = wlo2 + off;
    } else {
        int e = idx - 180224;
        int k = e >> 6, n = e & 63;
        w = root2[e];
        int off = fragoff(k, n, 4);
        hp = whiR2 + off; lp = wloR2 + off;
    }
    unsigned short h = f2bf(w);
    unsigned short l = f2bf(w - bf2f(h));
    *hp = (short)h;
    *lp = (short)l;
}

// ---------------- projection GEMM: C[M,128] = relu(A[M,K] @ B[K,128] + bias) ----
__global__ __launch_bounds__(256) void gemm_kernel(const float* __restrict__ A,
                                                   const float* __restrict__ B,
                                                   const float* __restrict__ bias,
                                                   float* __restrict__ C, int M, int K) {
    __shared__ float sA[64 * 128];
    int tid = threadIdx.x;
    int row0 = blockIdx.x * 64;

    for (int i = tid; i < (64 * K) >> 2; i += 256) {
        int off = i << 2;
        int rr = off / K, cc = off % K;
        int row = row0 + rr;
        float4 v = {0.f, 0.f, 0.f, 0.f};
        if (row < M) v = *(const float4*)(A + (long)row * K + cc);
        *(float4*)(sA + rr * K + cc) = v;
    }
    __syncthreads();

    int cg = tid & 31, rg = tid >> 5;
    int c0 = cg * 4, r0 = rg * 8;
    float acc[8][4];
#pragma unroll
    for (int i = 0; i < 8; i++)
#pragma unroll
        for (int j = 0; j < 4; j++) acc[i][j] = 0.f;

#pragma unroll 2
    for (int k = 0; k < K; k += 4) {
        float a[8][4];
#pragma unroll
        for (int i = 0; i < 8; i++)
            *(float4*)(a[i]) = *(const float4*)(sA + (r0 + i) * K + k);
#pragma unroll
        for (int j = 0; j < 4; j++) {
            float b[4];
            *(float4*)b = *(const float4*)(B + (k + j) * 128 + c0);
#pragma unroll
            for (int i = 0; i < 8; i++)
#pragma unroll
                for (int jj = 0; jj < 4; jj++)
                    acc[i][jj] = fmaf(a[i][j], b[jj], acc[i][jj]);
        }
    }

#pragma unroll
    for (int i = 0; i < 8; i++) {
        int row = row0 + r0 + i;
        if (row >= M) continue;
        float v[4];
#pragma unroll
        for (int jj = 0; jj < 4; jj++) v[jj] = fmaxf(acc[i][jj] + bias[c0 + jj], 0.f);
        *(float4*)(C + (long)row * 128 + c0) = *(float4*)v;
    }
}

// ---------------- fused dst-centric RGCN conv, split-bf16 MFMA ----------------
// Edge-parallel gather (NO serial per-row chains): per relation phase, the
// block's 64 bins form one contiguous srcSorted range [R0,R1). Work units =
// (edge, slice) pairs flat-distributed over all 512 threads; every x float4
// load is independent (full MLP, no straggler convoy), accumulated into an
// fp32 LDS tile via ds_add_f32. Slice-interleaved columns put an edge's 8
// lanes in 8 distinct banks. Mean scale + bf16 hi/lo split moved into the
// consumer (read fp32, *1/deg, convert, 3-term MFMA). LDS ~35.3KB -> 4 blk/CU.
template <int NC, bool HASROOT, bool DORELU>
__global__ __launch_bounds__(512) void conv_kernel(const float* __restrict__ x,
                                                   const short* __restrict__ whiRel,
                                                   const short* __restrict__ wloRel,
                                                   const short* __restrict__ whiRoot,
                                                   const short* __restrict__ wloRoot,
                                                   const int* __restrict__ binStart,
                                                   const int* __restrict__ binEnd,
                                                   const int* __restrict__ srcSorted,
                                                   float* __restrict__ out) {
    constexpr int NB  = NC / 16;   // col tiles: 8 (NC=128) or 4 (NC=64)
    constexpr int KB  = HIDC / 32; // 4 K-chunks
    constexpr int TPW = NB / 2;    // col tiles per wave-half: 4 or 2
    __shared__ float sAcc[64 * LDAF];
    __shared__ float sInv[64];
    int tid = threadIdx.x;
    int v0 = blockIdx.x * 64;

    const int wave = tid >> 6, lane = tid & 63;
    const int lrow = lane & 15, lgrp = lane >> 4;
    const int rt = wave >> 1, ch = wave & 1;  // row tile, col half
    const int myrow = rt * 16 + lrow;         // this thread's A row (constant)

    f32x4 acc[TPW];
#pragma unroll
    for (int t = 0; t < TPW; t++) acc[t] = (f32x4){0.f, 0.f, 0.f, 0.f};

    constexpr int NPHASE = HASROOT ? RELS + 1 : RELS;
#pragma unroll 1
    for (int ph = 0; ph < NPHASE; ph++) {
        if (ph > 0) __syncthreads();  // previous consumers done with sAcc
        if (ph < RELS) {
            // zero the accumulator tile + per-row 1/deg
#pragma unroll
            for (int i = 0; i < 4; i++) {
                int u = tid + 512 * i;  // 2048 float4 = 64 rows x 32 float4
                int row = u >> 5, c4 = u & 31;
                *(float4*)(sAcc + row * LDAF + c4 * 4) = make_float4(0.f, 0.f, 0.f, 0.f);
            }
            if (tid < 64) {
                int bin = ph * NNODES + v0 + tid;
                int d = binEnd[bin] - binStart[bin];
                sInv[tid] = 1.0f / (float)max(d, 1);
            }
            __syncthreads();
            // edge-parallel accumulate over the contiguous range
            int R0 = binStart[ph * NNODES + v0];
            int R1 = binEnd[ph * NNODES + v0 + 63];
            int nwork = (R1 - R0) << 3;  // 8 slices per edge
            for (int u = tid; u < nwork; u += 512) {
                int word = srcSorted[R0 + (u >> 3)];
                int sl = u & 7;
                int idx = word & 0x3FFFF, row = word >> 18;
                const float* xs = x + (long)idx * HIDC;
                float* dp = sAcc + row * LDAF;
#pragma unroll
                for (int i = 0; i < 4; i++) {
                    int c = (sl + i * 8) * 4;  // slice-interleaved: 8 lanes -> 8 banks
                    float4 v = *(const float4*)(xs + c);
                    atomicAdd(dp + c + 0, v.x);
                    atomicAdd(dp + c + 1, v.y);
                    atomicAdd(dp + c + 2, v.z);
                    atomicAdd(dp + c + 3, v.w);
                }
            }
        } else {
            // root phase: coalesced fp32 copy of the block's own 64 x-rows
#pragma unroll
            for (int i = 0; i < 4; i++) {
                int u = tid + 512 * i;
                int row = u >> 5, c4 = u & 31;
                *(float4*)(sAcc + row * LDAF + c4 * 4) =
                    *(const float4*)(x + (long)(v0 + row) * HIDC + c4 * 4);
            }
            if (tid < 64) sInv[tid] = 1.0f;
        }
        __syncthreads();

        const short* __restrict__ bhB = (ph < RELS) ? (whiRel + ph * (KB * NB * 512)) : whiRoot;
        const short* __restrict__ blB = (ph < RELS) ? (wloRel + ph * (KB * NB * 512)) : wloRoot;
        float sc = sInv[myrow];

#pragma unroll
        for (int kb = 0; kb < KB; kb++) {
            const float* ap = sAcc + myrow * LDAF + kb * 32 + lgrp * 8;
            float4 a0 = *(const float4*)(ap);
            float4 a1 = *(const float4*)(ap + 4);
            float f[8] = {a0.x * sc, a0.y * sc, a0.z * sc, a0.w * sc,
                          a1.x * sc, a1.y * sc, a1.z * sc, a1.w * sc};
            bf16x8 ah, al;
#pragma unroll
            for (int i2 = 0; i2 < 8; i2++) {
                unsigned short h = f2bf(f[i2]);
                ah[i2] = (short)h;
                al[i2] = (short)f2bf(f[i2] - bf2f(h));
            }
#pragma unroll
            for (int t = 0; t < TPW; t++) {
                int nb = ch * TPW + t;
                int boff = ((kb * NB + nb) * 64 + lane) * 8;
                bf16x8 bh = *(const bf16x8*)(bhB + boff);
                bf16x8 bl = *(const bf16x8*)(blB + boff);
                acc[t] = __builtin_amdgcn_mfma_f32_16x16x32_bf16(ah, bh, acc[t], 0, 0, 0);
                acc[t] = __builtin_amdgcn_mfma_f32_16x16x32_bf16(al, bh, acc[t], 0, 0, 0);
                acc[t] = __builtin_amdgcn_mfma_f32_16x16x32_bf16(ah, bl, acc[t], 0, 0, 0);
            }
        }
    }

    // epilogue: C/D layout col=lane&15, row=(lane>>4)*4+reg (HW-verified)
#pragma unroll
    for (int t = 0; t < TPW; t++) {
        int nb = ch * TPW + t;
        int col = nb * 16 + lrow;
#pragma unroll
        for (int j = 0; j < 4; j++) {
            float vv = acc[t][j];
            if (DORELU) vv = fmaxf(vv, 0.f);
            out[(long)(v0 + rt * 16 + lgrp * 4 + j) * NC + col] = vv;
        }
    }
}

// ---------------- launch ----------------

extern "C" void kernel_launch(void* const* d_in, const int* in_sizes, int n_in,
                              void* d_out, int out_size, void* d_ws, size_t ws_size,
                              hipStream_t stream) {
    const float* xa     = (const float*)d_in[0];
    const float* xp     = (const float*)d_in[1];
    const int*   src    = (const int*)d_in[2];
    const int*   dst    = (const int*)d_in[3];
    const int*   et     = (const int*)d_in[4];
    const float* Wpa    = (const float*)d_in[5];
    const float* bpa    = (const float*)d_in[6];
    const float* Wpb    = (const float*)d_in[7];
    const float* bpb    = (const float*)d_in[8];
    const float* basis0 = (const float*)d_in[9];
    const float* comp0  = (const float*)d_in[10];
    const float* basis1 = (const float*)d_in[11];
    const float* comp1  = (const float*)d_in[12];
    const float* root1  = (const float*)d_in[13];
    const float* basis2 = (const float*)d_in[14];
    const float* comp2  = (const float*)d_in[15];
    const float* root2  = (const float*)d_in[16];

    // d_out layout: final [N,64] | x_lat0 [N,128] | x_lat1 [N,128] | x_lat2 [N,128]
    float* out_final = (float*)d_out;
    float* x0 = out_final + (size_t)NNODES * OUTCH;
    float* x1 = x0 + (size_t)NNODES * HIDC;
    float* x2 = x1 + (size_t)NNODES * HIDC;

    // workspace (~9.56 MB)
    int* bins      = (int*)d_ws;            // 800000: counts -> starts
    int* binCur    = bins + SCAN_N;         // 800000: cursor -> ends
    int* blockSums = binCur + SCAN_N;       // 800
    int* srcSorted = blockSums + 800;       // 600000 packed (row<<18 | src)
    short* whi0  = (short*)(srcSorted + NEDGE);  // 65536
    short* wlo0  = whi0 + 65536;
    short* whi1  = wlo0 + 65536;                 // 65536
    short* wlo1  = whi1 + 65536;
    short* whiR1 = wlo1 + 65536;                 // 16384
    short* wloR1 = whiR1 + 16384;
    short* whi2  = wloR1 + 16384;                // 32768
    short* wlo2  = whi2 + 32768;
    short* whiR2 = wlo2 + 32768;                 // 8192
    short* wloR2 = whiR2 + 8192;

    dim3 b256(256);
    dim3 b512(512);
    int egrid = (NEDGE + 255) / 256;
    int nScanBlocks = (SCAN_N + 1023) / 1024;  // 782

    // ---- counting-sort of packed ids by (relation, dst) ----
    hipMemsetAsync(bins, 0, (size_t)SCAN_N * sizeof(int), stream);
    hipLaunchKernelGGL(count_kernel, dim3(egrid), b256, 0, stream, dst, et, bins);
    hipLaunchKernelGGL(scan1_kernel, dim3(nScanBlocks), b256, 0, stream, bins, blockSums);
    hipLaunchKernelGGL(scan2_kernel, dim3(1), b256, 0, stream, blockSums, nScanBlocks);
    hipLaunchKernelGGL(scan3_kernel, dim3((SCAN_N + 255) / 256), b256, 0, stream,
                       bins, blockSums, binCur);
    hipLaunchKernelGGL(scatter_kernel, dim3(egrid), b256, 0, stream,
                       src, dst, et, binCur, srcSorted);

    // ---- materialize relation+root weights as bf16 hi/lo MFMA fragments ----
    hipLaunchKernelGGL(fragify_kernel, dim3((188416 + 255) / 256), b256, 0, stream,
                       basis0, comp0, basis1, comp1, root1, basis2, comp2, root2,
                       whi0, wlo0, whi1, wlo1, whiR1, wloR1, whi2, wlo2, whiR2, wloR2);

    // ---- projections -> x_lat0 ----
    hipLaunchKernelGGL(gemm_kernel, dim3((NAUT + 63) / 64), b256, 0, stream,
                       xa, Wpa, bpa, x0, NAUT, 64);
    hipLaunchKernelGGL(gemm_kernel, dim3((NAUT + 63) / 64), b256, 0, stream,
                       xp, Wpb, bpb, x0 + (size_t)NAUT * HIDC, NAUT, 96);

    int cgrid = NNODES / 64;  // 3125, exact

    // conv0: x1 = relu(aggr(x0))            (no root)
    hipLaunchKernelGGL((conv_kernel<128, false, true>), dim3(cgrid), b512, 0, stream,
                       x0, whi0, wlo0, (const short*)nullptr, (const short*)nullptr,
                       bins, binCur, srcSorted, x1);
    // conv1: x2 = relu(x1 @ root1 + aggr(x1))
    hipLaunchKernelGGL((conv_kernel<128, true, true>), dim3(cgrid), b512, 0, stream,
                       x1, whi1, wlo1, whiR1, wloR1, bins, binCur, srcSorted, x2);
    // conv2: final = x2 @ root2 + aggr(x2)  (no relu)
    hipLaunchKernelGGL((conv_kernel<64, true, false>), dim3(cgrid), b512, 0, stream,
                       x2, whi2, wlo2, whiR2, wloR2, bins, binCur, srcSorted, out_final);
}

// Round 9
// 1328.210 us; speedup vs baseline: 1.5377x; 1.5377x over previous
//
#include <hip/hip_runtime.h>

// Problem constants (fixed by reference).
constexpr int NNODES = 200000;
constexpr int NAUT   = 100000;
constexpr int NEDGE  = 600000;
constexpr int HIDC   = 128;
constexpr int OUTCH  = 64;
constexpr int RELS   = 4;
constexpr int SCAN_N = RELS * NNODES;  // 800000 bins

typedef __attribute__((ext_vector_type(8))) short bf16x8;
typedef __attribute__((ext_vector_type(4))) float f32x4;

// ---------------- bf16 split helpers ----------------
__device__ __forceinline__ unsigned short f2bf(float f) {
    unsigned int b = __float_as_uint(f);
    b += 0x7FFFu + ((b >> 16) & 1u);  // round-to-nearest-even
    return (unsigned short)(b >> 16);
}
__device__ __forceinline__ float bf2f(unsigned short u) {
    return __uint_as_float(((unsigned int)u) << 16);
}

// MFMA B/A fragment offset for element (k,n) of a [128 x N] matrix, NB = N/16.
// Layout: [kb][nb][lane][j] with lane = ((k>>3)&3)*16 + (n&15), j = k&7.
__device__ __forceinline__ int fragoff(int k, int n, int NB) {
    return ((k >> 5) * NB + (n >> 4)) * 512 + (((k >> 3) & 3) * 16 + (n & 15)) * 8 + (k & 7);
}

// ---------------- prep kernels ----------------

// int count per (relation, dst) bin
__global__ void count_kernel(const int* __restrict__ dst, const int* __restrict__ et,
                             int* __restrict__ bins) {
    int e = blockIdx.x * 256 + threadIdx.x;
    if (e < NEDGE) atomicAdd(&bins[et[e] * NNODES + dst[e]], 1);
}

// ---- deterministic 3-phase exclusive scan (counts -> starts), in-place ----
__global__ void scan1_kernel(int* __restrict__ bins, int* __restrict__ blockSums) {
    __shared__ int s[256];
    int b = blockIdx.x, t = threadIdx.x;
    int base = b * 1024 + t * 4;
    int v[4], sum = 0;
#pragma unroll
    for (int i = 0; i < 4; i++) {
        v[i] = (base + i < SCAN_N) ? bins[base + i] : 0;
        sum += v[i];
    }
    s[t] = sum;
    __syncthreads();
    for (int off = 1; off < 256; off <<= 1) {
        int x = (t >= off) ? s[t - off] : 0;
        __syncthreads();
        if (t >= off) s[t] += x;
        __syncthreads();
    }
    int run = s[t] - sum;
    if (t == 255) blockSums[b] = s[255];
#pragma unroll
    for (int i = 0; i < 4; i++) {
        if (base + i < SCAN_N) bins[base + i] = run;
        run += v[i];
    }
}

__global__ void scan2_kernel(int* __restrict__ blockSums, int nb) {
    __shared__ int s[256];
    int t = threadIdx.x;
    int carry = 0;
    for (int base = 0; base < nb; base += 256) {
        int v = (base + t < nb) ? blockSums[base + t] : 0;
        s[t] = v;
        __syncthreads();
        for (int off = 1; off < 256; off <<= 1) {
            int x = (t >= off) ? s[t - off] : 0;
            __syncthreads();
            if (t >= off) s[t] += x;
            __syncthreads();
        }
        if (base + t < nb) blockSums[base + t] = carry + (s[t] - v);
        int total = s[255];
        __syncthreads();
        carry += total;
    }
}

__global__ void scan3_kernel(int* __restrict__ bins, const int* __restrict__ blockSums,
                             int* __restrict__ binCur) {
    int i = blockIdx.x * 256 + threadIdx.x;
    if (i < SCAN_N) {
        int v = bins[i] + blockSums[i >> 10];
        bins[i] = v;
        binCur[i] = v;
    }
}

// scatter src ids into (relation,dst)-sorted order; binCur becomes end-offsets
__global__ void scatter_kernel(const int* __restrict__ src, const int* __restrict__ dst,
                               const int* __restrict__ et, int* __restrict__ binCur,
                               int* __restrict__ srcSorted) {
    int e = blockIdx.x * 256 + threadIdx.x;
    if (e < NEDGE) {
        int bin = et[e] * NNODES + dst[e];
        int pos = atomicAdd(&binCur[bin], 1);
        srcSorted[pos] = src[e];
    }
}

// Build all relation/root weights directly into MFMA B-fragment layout,
// split into bf16 hi/lo pairs. One thread per matrix element.
__global__ void fragify_kernel(const float* __restrict__ basis0, const float* __restrict__ comp0,
                               const float* __restrict__ basis1, const float* __restrict__ comp1,
                               const float* __restrict__ root1,
                               const float* __restrict__ basis2, const float* __restrict__ comp2,
                               const float* __restrict__ root2,
                               short* __restrict__ whi0, short* __restrict__ wlo0,
                               short* __restrict__ whi1, short* __restrict__ wlo1,
                               short* __restrict__ whiR1, short* __restrict__ wloR1,
                               short* __restrict__ whi2, short* __restrict__ wlo2,
                               short* __restrict__ whiR2, short* __restrict__ wloR2) {
    int idx = blockIdx.x * 256 + threadIdx.x;
    if (idx >= 188416) return;
    float w;
    short *hp, *lp;
    if (idx < 65536) {
        int r = idx >> 14, e = idx & 16383;
        int k = e >> 7, n = e & 127;
        w = 0.f;
#pragma unroll
        for (int b = 0; b < 4; b++) w += comp0[r * 4 + b] * basis0[b * 16384 + e];
        int off = r * 16384 + fragoff(k, n, 8);
        hp = whi0 + off; lp = wlo0 + off;
    } else if (idx < 131072) {
        int i2 = idx - 65536;
        int r = i2 >> 14, e = i2 & 16383;
        int k = e >> 7, n = e & 127;
        w = 0.f;
#pragma unroll
        for (int b = 0; b < 4; b++) w += comp1[r * 4 + b] * basis1[b * 16384 + e];
        int off = r * 16384 + fragoff(k, n, 8);
        hp = whi1 + off; lp = wlo1 + off;
    } else if (idx < 147456) {
        int e = idx - 131072;
        int k = e >> 7, n = e & 127;
        w = root1[e];
        int off = fragoff(k, n, 8);
        hp = whiR1 + off; lp = wloR1 + off;
    } else if (idx < 180224) {
        int i2 = idx - 147456;
        int r = i2 >> 13, e = i2 & 8191;
        int k = e >> 6, n = e & 63;
        w = 0.f;
#pragma unroll
        for (int b = 0; b < 4; b++) w += comp2[r * 4 + b] * basis2[b * 8192 + e];
        int off = r * 8192 + fragoff(k, n, 4);
        hp = whi2 + off; lp = wlo2 + off;
    } else {
        int e = idx - 180224;
        int k = e >> 6, n = e & 63;
        w = root2[e];
        int off = fragoff(k, n, 4);
        hp = whiR2 + off; lp = wloR2 + off;
    }
    unsigned short h = f2bf(w);
    unsigned short l = f2bf(w - bf2f(h));
    *hp = (short)h;
    *lp = (short)l;
}

// ---------------- projection GEMM: C[M,128] = relu(A[M,K] @ B[K,128] + bias) ----
__global__ __launch_bounds__(256) void gemm_kernel(const float* __restrict__ A,
                                                   const float* __restrict__ B,
                                                   const float* __restrict__ bias,
                                                   float* __restrict__ C, int M, int K) {
    __shared__ float sA[64 * 128];
    int tid = threadIdx.x;
    int row0 = blockIdx.x * 64;

    for (int i = tid; i < (64 * K) >> 2; i += 256) {
        int off = i << 2;
        int rr = off / K, cc = off % K;
        int row = row0 + rr;
        float4 v = {0.f, 0.f, 0.f, 0.f};
        if (row < M) v = *(const float4*)(A + (long)row * K + cc);
        *(float4*)(sA + rr * K + cc) = v;
    }
    __syncthreads();

    int cg = tid & 31, rg = tid >> 5;
    int c0 = cg * 4, r0 = rg * 8;
    float acc[8][4];
#pragma unroll
    for (int i = 0; i < 8; i++)
#pragma unroll
        for (int j = 0; j < 4; j++) acc[i][j] = 0.f;

#pragma unroll 2
    for (int k = 0; k < K; k += 4) {
        float a[8][4];
#pragma unroll
        for (int i = 0; i < 8; i++)
            *(float4*)(a[i]) = *(const float4*)(sA + (r0 + i) * K + k);
#pragma unroll
        for (int j = 0; j < 4; j++) {
            float b[4];
            *(float4*)b = *(const float4*)(B + (k + j) * 128 + c0);
#pragma unroll
            for (int i = 0; i < 8; i++)
#pragma unroll
                for (int jj = 0; jj < 4; jj++)
                    acc[i][jj] = fmaf(a[i][j], b[jj], acc[i][jj]);
        }
    }

#pragma unroll
    for (int i = 0; i < 8; i++) {
        int row = row0 + r0 + i;
        if (row >= M) continue;
        float v[4];
#pragma unroll
        for (int jj = 0; jj < 4; jj++) v[jj] = fmaxf(acc[i][jj] + bias[c0 + jj], 0.f);
        *(float4*)(C + (long)row * 128 + c0) = *(float4*)v;
    }
}

// ---------------- fused dst-centric RGCN conv: ZERO-LDS, ZERO-BARRIER ----------
// Each thread gathers its OWN MFMA A-fragment straight from x into registers:
// lane (lrow,lgrp) of wave (rt,ch) owns row rt*16+lrow, k-octet kb*32+lgrp*8.
// Per (rel, kb): sum the row's sorted-contiguous edges over 8 cols (2 float4
// loads/edge), scale by 1/deg, split to bf16 hi/lo, 3-term MFMA vs W frags.
// No __syncthreads anywhere -> no max-degree barrier convoy; waves independent;
// no LDS -> occupancy capped only by waves/VGPR (<=64 VGPR -> 32 waves/CU,
// double the whole session). Cost: ch-halves duplicate the gather (~2x fetch,
// still far under BW roofline). Register budget kept small deliberately; no
// min-waves __launch_bounds__ pin (r1/r6 lesson: it forces spills).
template <int NC, bool HASROOT, bool DORELU>
__global__ __launch_bounds__(512) void conv_kernel(const float* __restrict__ x,
                                                   const short* __restrict__ whiRel,
                                                   const short* __restrict__ wloRel,
                                                   const short* __restrict__ whiRoot,
                                                   const short* __restrict__ wloRoot,
                                                   const int* __restrict__ binStart,
                                                   const int* __restrict__ binEnd,
                                                   const int* __restrict__ srcSorted,
                                                   float* __restrict__ out) {
    constexpr int NB  = NC / 16;   // col tiles: 8 (NC=128) or 4 (NC=64)
    constexpr int KB  = HIDC / 32; // 4 K-chunks
    constexpr int TPW = NB / 2;    // col tiles per wave-half: 4 or 2
    int tid = threadIdx.x;
    int v0 = blockIdx.x * 64;

    const int wave = tid >> 6, lane = tid & 63;
    const int lrow = lane & 15, lgrp = lane >> 4;
    const int rt = wave >> 1, ch = wave & 1;  // row tile, col half
    const int myrow = rt * 16 + lrow;         // this thread's A row

    f32x4 acc[TPW];
#pragma unroll
    for (int t = 0; t < TPW; t++) acc[t] = (f32x4){0.f, 0.f, 0.f, 0.f};

    constexpr int NPHASE = HASROOT ? RELS + 1 : RELS;
#pragma unroll 1
    for (int ph = 0; ph < NPHASE; ph++) {
        const short* __restrict__ bhB = (ph < RELS) ? (whiRel + ph * (KB * NB * 512)) : whiRoot;
        const short* __restrict__ blB = (ph < RELS) ? (wloRel + ph * (KB * NB * 512)) : wloRoot;
        int s = 0, e = 0;
        float sc = 1.0f;
        if (ph < RELS) {
            int bin = ph * NNODES + v0 + myrow;
            s = binStart[bin];
            e = binEnd[bin];
            sc = 1.0f / (float)max(e - s, 1);
        }

#pragma unroll 1
        for (int kb = 0; kb < KB; kb++) {
            const int coff = kb * 32 + lgrp * 8;  // this thread's 8-col octet
            float4 a0, a1;
            if (ph < RELS) {
                a0 = make_float4(0.f, 0.f, 0.f, 0.f);
                a1 = make_float4(0.f, 0.f, 0.f, 0.f);
                for (int j = s; j < e; j++) {
                    const float* xs = x + (long)srcSorted[j] * HIDC + coff;
                    float4 u0 = *(const float4*)(xs);
                    float4 u1 = *(const float4*)(xs + 4);
                    a0.x += u0.x; a0.y += u0.y; a0.z += u0.z; a0.w += u0.w;
                    a1.x += u1.x; a1.y += u1.y; a1.z += u1.z; a1.w += u1.w;
                }
                a0.x *= sc; a0.y *= sc; a0.z *= sc; a0.w *= sc;
                a1.x *= sc; a1.y *= sc; a1.z *= sc; a1.w *= sc;
            } else {
                const float* xs = x + (long)(v0 + myrow) * HIDC + coff;
                a0 = *(const float4*)(xs);
                a1 = *(const float4*)(xs + 4);
            }
            float f[8] = {a0.x, a0.y, a0.z, a0.w, a1.x, a1.y, a1.z, a1.w};
            bf16x8 ah, al;
#pragma unroll
            for (int i2 = 0; i2 < 8; i2++) {
                unsigned short h = f2bf(f[i2]);
                ah[i2] = (short)h;
                al[i2] = (short)f2bf(f[i2] - bf2f(h));
            }
#pragma unroll
            for (int t = 0; t < TPW; t++) {
                int nb = ch * TPW + t;
                int boff = ((kb * NB + nb) * 64 + lane) * 8;
                bf16x8 bh = *(const bf16x8*)(bhB + boff);
                bf16x8 bl = *(const bf16x8*)(blB + boff);
                acc[t] = __builtin_amdgcn_mfma_f32_16x16x32_bf16(ah, bh, acc[t], 0, 0, 0);
                acc[t] = __builtin_amdgcn_mfma_f32_16x16x32_bf16(al, bh, acc[t], 0, 0, 0);
                acc[t] = __builtin_amdgcn_mfma_f32_16x16x32_bf16(ah, bl, acc[t], 0, 0, 0);
            }
        }
    }

    // epilogue: C/D layout col=lane&15, row=(lane>>4)*4+reg (HW-verified)
#pragma unroll
    for (int t = 0; t < TPW; t++) {
        int nb = ch * TPW + t;
        int col = nb * 16 + lrow;
#pragma unroll
        for (int j = 0; j < 4; j++) {
            float vv = acc[t][j];
            if (DORELU) vv = fmaxf(vv, 0.f);
            out[(long)(v0 + rt * 16 + lgrp * 4 + j) * NC + col] = vv;
        }
    }
}

// ---------------- launch ----------------

extern "C" void kernel_launch(void* const* d_in, const int* in_sizes, int n_in,
                              void* d_out, int out_size, void* d_ws, size_t ws_size,
                              hipStream_t stream) {
    const float* xa     = (const float*)d_in[0];
    const float* xp     = (const float*)d_in[1];
    const int*   src    = (const int*)d_in[2];
    const int*   dst    = (const int*)d_in[3];
    const int*   et     = (const int*)d_in[4];
    const float* Wpa    = (const float*)d_in[5];
    const float* bpa    = (const float*)d_in[6];
    const float* Wpb    = (const float*)d_in[7];
    const float* bpb    = (const float*)d_in[8];
    const float* basis0 = (const float*)d_in[9];
    const float* comp0  = (const float*)d_in[10];
    const float* basis1 = (const float*)d_in[11];
    const float* comp1  = (const float*)d_in[12];
    const float* root1  = (const float*)d_in[13];
    const float* basis2 = (const float*)d_in[14];
    const float* comp2  = (const float*)d_in[15];
    const float* root2  = (const float*)d_in[16];

    // d_out layout: final [N,64] | x_lat0 [N,128] | x_lat1 [N,128] | x_lat2 [N,128]
    float* out_final = (float*)d_out;
    float* x0 = out_final + (size_t)NNODES * OUTCH;
    float* x1 = x0 + (size_t)NNODES * HIDC;
    float* x2 = x1 + (size_t)NNODES * HIDC;

    // workspace (~9.56 MB)
    int* bins      = (int*)d_ws;            // 800000: counts -> starts
    int* binCur    = bins + SCAN_N;         // 800000: cursor -> ends
    int* blockSums = binCur + SCAN_N;       // 800
    int* srcSorted = blockSums + 800;       // 600000
    short* whi0  = (short*)(srcSorted + NEDGE);  // 65536
    short* wlo0  = whi0 + 65536;
    short* whi1  = wlo0 + 65536;                 // 65536
    short* wlo1  = whi1 + 65536;
    short* whiR1 = wlo1 + 65536;                 // 16384
    short* wloR1 = whiR1 + 16384;
    short* whi2  = wloR1 + 16384;                // 32768
    short* wlo2  = whi2 + 32768;
    short* whiR2 = wlo2 + 32768;                 // 8192
    short* wloR2 = whiR2 + 8192;

    dim3 b256(256);
    dim3 b512(512);
    int egrid = (NEDGE + 255) / 256;
    int nScanBlocks = (SCAN_N + 1023) / 1024;  // 782

    // ---- counting-sort of src ids by (relation, dst) ----
    hipMemsetAsync(bins, 0, (size_t)SCAN_N * sizeof(int), stream);
    hipLaunchKernelGGL(count_kernel, dim3(egrid), b256, 0, stream, dst, et, bins);
    hipLaunchKernelGGL(scan1_kernel, dim3(nScanBlocks), b256, 0, stream, bins, blockSums);
    hipLaunchKernelGGL(scan2_kernel, dim3(1), b256, 0, stream, blockSums, nScanBlocks);
    hipLaunchKernelGGL(scan3_kernel, dim3((SCAN_N + 255) / 256), b256, 0, stream,
                       bins, blockSums, binCur);
    hipLaunchKernelGGL(scatter_kernel, dim3(egrid), b256, 0, stream,
                       src, dst, et, binCur, srcSorted);

    // ---- materialize relation+root weights as bf16 hi/lo MFMA fragments ----
    hipLaunchKernelGGL(fragify_kernel, dim3((188416 + 255) / 256), b256, 0, stream,
                       basis0, comp0, basis1, comp1, root1, basis2, comp2, root2,
                       whi0, wlo0, whi1, wlo1, whiR1, wloR1, whi2, wlo2, whiR2, wloR2);

    // ---- projections -> x_lat0 ----
    hipLaunchKernelGGL(gemm_kernel, dim3((NAUT + 63) / 64), b256, 0, stream,
                       xa, Wpa, bpa, x0, NAUT, 64);
    hipLaunchKernelGGL(gemm_kernel, dim3((NAUT + 63) / 64), b256, 0, stream,
                       xp, Wpb, bpb, x0 + (size_t)NAUT * HIDC, NAUT, 96);

    int cgrid = NNODES / 64;  // 3125, exact

    // conv0: x1 = relu(aggr(x0))            (no root)
    hipLaunchKernelGGL((conv_kernel<128, false, true>), dim3(cgrid), b512, 0, stream,
                       x0, whi0, wlo0, (const short*)nullptr, (const short*)nullptr,
                       bins, binCur, srcSorted, x1);
    // conv1: x2 = relu(x1 @ root1 + aggr(x1))
    hipLaunchKernelGGL((conv_kernel<128, true, true>), dim3(cgrid), b512, 0, stream,
                       x1, whi1, wlo1, whiR1, wloR1, bins, binCur, srcSorted, x2);
    // conv2: final = x2 @ root2 + aggr(x2)  (no relu)
    hipLaunchKernelGGL((conv_kernel<64, true, false>), dim3(cgrid), b512, 0, stream,
                       x2, whi2, wlo2, whiR2, wloR2, bins, binCur, srcSorted, out_final);
}

// Round 10
// 1267.145 us; speedup vs baseline: 1.6118x; 1.0482x over previous
//
#include <hip/hip_runtime.h>

// Problem constants (fixed by reference).
constexpr int NNODES = 200000;
constexpr int NAUT   = 100000;
constexpr int NEDGE  = 600000;
constexpr int HIDC   = 128;
constexpr int OUTCH  = 64;
constexpr int RELS   = 4;
constexpr int SCAN_N = RELS * NNODES;  // 800000 bins
constexpr int LDB    = HIDC + 8;       // bf16 LDS row stride (272B)

typedef __attribute__((ext_vector_type(8))) short bf16x8;
typedef __attribute__((ext_vector_type(4))) float f32x4;

// ---------------- bf16 split helpers ----------------
__device__ __forceinline__ unsigned short f2bf(float f) {
    unsigned int b = __float_as_uint(f);
    b += 0x7FFFu + ((b >> 16) & 1u);  // round-to-nearest-even
    return (unsigned short)(b >> 16);
}
__device__ __forceinline__ float bf2f(unsigned short u) {
    return __uint_as_float(((unsigned int)u) << 16);
}

// MFMA B/A fragment offset for element (k,n) of a [128 x N] matrix, NB = N/16.
// Layout: [kb][nb][lane][j] with lane = ((k>>3)&3)*16 + (n&15), j = k&7.
__device__ __forceinline__ int fragoff(int k, int n, int NB) {
    return ((k >> 5) * NB + (n >> 4)) * 512 + (((k >> 3) & 3) * 16 + (n & 15)) * 8 + (k & 7);
}

// ---------------- prep kernels ----------------

// int count per (relation, dst) bin
__global__ void count_kernel(const int* __restrict__ dst, const int* __restrict__ et,
                             int* __restrict__ bins) {
    int e = blockIdx.x * 256 + threadIdx.x;
    if (e < NEDGE) atomicAdd(&bins[et[e] * NNODES + dst[e]], 1);
}

// ---- fused single-pass scan over 800k bins (counts -> starts + cursor) ----
// Per-block exclusive scan; block base via one atomicAdd of the block total.
// Bin-segment ordering is nondeterministic, which is fine: the conv gather
// only needs each bin's neighbors contiguous (per-bin [start,end) bounds).
__global__ void scan_fused_kernel(int* __restrict__ bins, int* __restrict__ binCur,
                                  int* __restrict__ gctr) {
    __shared__ int s[256];
    __shared__ int sbase;
    int b = blockIdx.x, t = threadIdx.x;
    int base = b * 1024 + t * 4;
    int v[4], sum = 0;
#pragma unroll
    for (int i = 0; i < 4; i++) {
        v[i] = (base + i < SCAN_N) ? bins[base + i] : 0;
        sum += v[i];
    }
    s[t] = sum;
    __syncthreads();
    for (int off = 1; off < 256; off <<= 1) {
        int x = (t >= off) ? s[t - off] : 0;
        __syncthreads();
        if (t >= off) s[t] += x;
        __syncthreads();
    }
    if (t == 255) sbase = atomicAdd(gctr, s[255]);
    __syncthreads();
    int run = sbase + s[t] - sum;
#pragma unroll
    for (int i = 0; i < 4; i++) {
        if (base + i < SCAN_N) {
            bins[base + i] = run;
            binCur[base + i] = run;
        }
        run += v[i];
    }
}

__global__ void scatter_kernel(const int* __restrict__ src, const int* __restrict__ dst,
                               const int* __restrict__ et, int* __restrict__ binCur,
                               int* __restrict__ srcSorted) {
    int e = blockIdx.x * 256 + threadIdx.x;
    if (e < NEDGE) {
        int bin = et[e] * NNODES + dst[e];
        int pos = atomicAdd(&binCur[bin], 1);
        srcSorted[pos] = src[e];
    }
}

// Build all relation/root weights directly into MFMA B-fragment layout,
// split into bf16 hi/lo pairs. One thread per matrix element.
__global__ void fragify_kernel(const float* __restrict__ basis0, const float* __restrict__ comp0,
                               const float* __restrict__ basis1, const float* __restrict__ comp1,
                               const float* __restrict__ root1,
                               const float* __restrict__ basis2, const float* __restrict__ comp2,
                               const float* __restrict__ root2,
                               short* __restrict__ whi0, short* __restrict__ wlo0,
                               short* __restrict__ whi1, short* __restrict__ wlo1,
                               short* __restrict__ whiR1, short* __restrict__ wloR1,
                               short* __restrict__ whi2, short* __restrict__ wlo2,
                               short* __restrict__ whiR2, short* __restrict__ wloR2) {
    int idx = blockIdx.x * 256 + threadIdx.x;
    if (idx >= 188416) return;
    float w;
    short *hp, *lp;
    if (idx < 65536) {
        int r = idx >> 14, e = idx & 16383;
        int k = e >> 7, n = e & 127;
        w = 0.f;
#pragma unroll
        for (int b = 0; b < 4; b++) w += comp0[r * 4 + b] * basis0[b * 16384 + e];
        int off = r * 16384 + fragoff(k, n, 8);
        hp = whi0 + off; lp = wlo0 + off;
    } else if (idx < 131072) {
        int i2 = idx - 65536;
        int r = i2 >> 14, e = i2 & 16383;
        int k = e >> 7, n = e & 127;
        w = 0.f;
#pragma unroll
        for (int b = 0; b < 4; b++) w += comp1[r * 4 + b] * basis1[b * 16384 + e];
        int off = r * 16384 + fragoff(k, n, 8);
        hp = whi1 + off; lp = wlo1 + off;
    } else if (idx < 147456) {
        int e = idx - 131072;
        int k = e >> 7, n = e & 127;
        w = root1[e];
        int off = fragoff(k, n, 8);
        hp = whiR1 + off; lp = wloR1 + off;
    } else if (idx < 180224) {
        int i2 = idx - 147456;
        int r = i2 >> 13, e = i2 & 8191;
        int k = e >> 6, n = e & 63;
        w = 0.f;
#pragma unroll
        for (int b = 0; b < 4; b++) w += comp2[r * 4 + b] * basis2[b * 8192 + e];
        int off = r * 8192 + fragoff(k, n, 4);
        hp = whi2 + off; lp = wlo2 + off;
    } else {
        int e = idx - 180224;
        int k = e >> 6, n = e & 63;
        w = root2[e];
        int off = fragoff(k, n, 4);
        hp = whiR2 + off; lp = wloR2 + off;
    }
    unsigned short h = f2bf(w);
    unsigned short l = f2bf(w - bf2f(h));
    *hp = (short)h;
    *lp = (short)l;
}

// ---------------- projection GEMM: C[M,128] = relu(A[M,K] @ B[K,128] + bias) ----
__global__ __launch_bounds__(256) void gemm_kernel(const float* __restrict__ A,
                                                   const float* __restrict__ B,
                                                   const float* __restrict__ bias,
                                                   float* __restrict__ C, int M, int K) {
    __shared__ float sA[64 * 128];
    int tid = threadIdx.x;
    int row0 = blockIdx.x * 64;

    for (int i = tid; i < (64 * K) >> 2; i += 256) {
        int off = i << 2;
        int rr = off / K, cc = off % K;
        int row = row0 + rr;
        float4 v = {0.f, 0.f, 0.f, 0.f};
        if (row < M) v = *(const float4*)(A + (long)row * K + cc);
        *(float4*)(sA + rr * K + cc) = v;
    }
    __syncthreads();

    int cg = tid & 31, rg = tid >> 5;
    int c0 = cg * 4, r0 = rg * 8;
    float acc[8][4];
#pragma unroll
    for (int i = 0; i < 8; i++)
#pragma unroll
        for (int j = 0; j < 4; j++) acc[i][j] = 0.f;

#pragma unroll 2
    for (int k = 0; k < K; k += 4) {
        float a[8][4];
#pragma unroll
        for (int i = 0; i < 8; i++)
            *(float4*)(a[i]) = *(const float4*)(sA + (r0 + i) * K + k);
#pragma unroll
        for (int j = 0; j < 4; j++) {
            float b[4];
            *(float4*)b = *(const float4*)(B + (k + j) * 128 + c0);
#pragma unroll
            for (int i = 0; i < 8; i++)
#pragma unroll
                for (int jj = 0; jj < 4; jj++)
                    acc[i][jj] = fmaf(a[i][j], b[jj], acc[i][jj]);
        }
    }

#pragma unroll
    for (int i = 0; i < 8; i++) {
        int row = row0 + r0 + i;
        if (row >= M) continue;
        float v[4];
#pragma unroll
        for (int jj = 0; jj < 4; jj++) v[jj] = fmaxf(acc[i][jj] + bias[c0 + jj], 0.f);
        *(float4*)(C + (long)row * 128 + c0) = *(float4*)v;
    }
}

// ---------------- fused dst-centric RGCN conv, split-bf16 MFMA ----------------
// r5 skeleton (256 thr, 64 dst rows, 2 barriers/phase, 3-term hi/lo MFMA) with
// WAVE-COALESCED gather: each wave owns 16 dst rows; for each row it walks the
// row's contiguous srcSorted range with ALL 64 lanes on the same edge -- the
// src index is a wave-uniform scalar load and the 512B source row is ONE
// coalesced global_load_dwordx2 (lane c accumulates cols 2c,2c+1). Per edge:
// 1 VMEM instruction instead of 32 scattered 16B loads; zero lane divergence;
// independent iterations pipeline (next-idx prefetch). Row means are scaled,
// split to bf16 hi/lo and staged via 2 packed ds_write_b32 (conflict-free).
template <int NC, bool HASROOT, bool DORELU>
__global__ __launch_bounds__(256) void conv_kernel(const float* __restrict__ x,
                                                   const short* __restrict__ whiRel,
                                                   const short* __restrict__ wloRel,
                                                   const short* __restrict__ whiRoot,
                                                   const short* __restrict__ wloRoot,
                                                   const int* __restrict__ binStart,
                                                   const int* __restrict__ binEnd,
                                                   const int* __restrict__ srcSorted,
                                                   float* __restrict__ out) {
    constexpr int NB  = NC / 16;   // col tiles: 8 (NC=128) or 4 (NC=64)
    constexpr int KB  = HIDC / 32; // 4 K-chunks
    constexpr int TPW = NB / 4;    // col tiles per wave: 2 or 1
    __shared__ short sHi[64 * LDB];
    __shared__ short sLo[64 * LDB];
    int tid = threadIdx.x;
    int v0 = blockIdx.x * 64;

    const int wave = tid >> 6, lane = tid & 63;
    const int lrow = lane & 15, lgrp = lane >> 4;
    const int c2 = lane * 2;       // this lane's 2 gather columns

    f32x4 acc[4][TPW];
#pragma unroll
    for (int rt = 0; rt < 4; rt++)
#pragma unroll
        for (int t = 0; t < TPW; t++) acc[rt][t] = (f32x4){0.f, 0.f, 0.f, 0.f};

    constexpr int NPHASE = HASROOT ? RELS + 1 : RELS;
#pragma unroll 1
    for (int ph = 0; ph < NPHASE; ph++) {
        if (ph > 0) __syncthreads();  // protect LDS from previous phase's readers
        if (ph < RELS) {
            // wave-coalesced gather: this wave owns rows wave*16 .. wave*16+15
#pragma unroll 1
            for (int rr = 0; rr < 16; rr++) {
                int row = wave * 16 + rr;
                int bin = ph * NNODES + v0 + row;
                int s = binStart[bin], e = binEnd[bin];
                float a0 = 0.f, a1 = 0.f;
                int j = s;
                int idx = (j < e) ? srcSorted[j] : 0;
#pragma unroll 1
                for (; j < e; j++) {
                    int nidx = (j + 1 < e) ? srcSorted[j + 1] : 0;
                    float2 u = *(const float2*)(x + (long)idx * HIDC + c2);
                    a0 += u.x;
                    a1 += u.y;
                    idx = nidx;
                }
                float sc = 1.0f / (float)max(e - s, 1);
                a0 *= sc; a1 *= sc;
                unsigned short h0 = f2bf(a0), h1 = f2bf(a1);
                unsigned short l0 = f2bf(a0 - bf2f(h0)), l1 = f2bf(a1 - bf2f(h1));
                *(unsigned int*)(sHi + row * LDB + c2) = (unsigned)h0 | ((unsigned)h1 << 16);
                *(unsigned int*)(sLo + row * LDB + c2) = (unsigned)l0 | ((unsigned)l1 << 16);
            }
        } else {
            // root phase: coalesced copy+convert of this wave's 16 own rows
#pragma unroll 1
            for (int rr = 0; rr < 16; rr++) {
                int row = wave * 16 + rr;
                float2 u = *(const float2*)(x + (long)(v0 + row) * HIDC + c2);
                unsigned short h0 = f2bf(u.x), h1 = f2bf(u.y);
                unsigned short l0 = f2bf(u.x - bf2f(h0)), l1 = f2bf(u.y - bf2f(h1));
                *(unsigned int*)(sHi + row * LDB + c2) = (unsigned)h0 | ((unsigned)h1 << 16);
                *(unsigned int*)(sLo + row * LDB + c2) = (unsigned)l0 | ((unsigned)l1 << 16);
            }
        }
        __syncthreads();

        const short* __restrict__ bhB = (ph < RELS) ? (whiRel + ph * (KB * NB * 512)) : whiRoot;
        const short* __restrict__ blB = (ph < RELS) ? (wloRel + ph * (KB * NB * 512)) : wloRoot;

#pragma unroll
        for (int kb = 0; kb < KB; kb++) {
            bf16x8 bh[TPW], bl[TPW];
#pragma unroll
            for (int t = 0; t < TPW; t++) {
                int nb = wave * TPW + t;
                int boff = ((kb * NB + nb) * 64 + lane) * 8;
                bh[t] = *(const bf16x8*)(bhB + boff);
                bl[t] = *(const bf16x8*)(blB + boff);
            }
#pragma unroll
            for (int rt = 0; rt < 4; rt++) {
                int aoff = (rt * 16 + lrow) * LDB + kb * 32 + lgrp * 8;
                bf16x8 ah = *(const bf16x8*)(sHi + aoff);
                bf16x8 al = *(const bf16x8*)(sLo + aoff);
#pragma unroll
                for (int t = 0; t < TPW; t++) {
                    acc[rt][t] = __builtin_amdgcn_mfma_f32_16x16x32_bf16(ah, bh[t], acc[rt][t], 0, 0, 0);
                    acc[rt][t] = __builtin_amdgcn_mfma_f32_16x16x32_bf16(al, bh[t], acc[rt][t], 0, 0, 0);
                    acc[rt][t] = __builtin_amdgcn_mfma_f32_16x16x32_bf16(ah, bl[t], acc[rt][t], 0, 0, 0);
                }
            }
        }
    }

    // epilogue: C/D layout col=lane&15, row=(lane>>4)*4+reg (HW-verified)
#pragma unroll
    for (int rt = 0; rt < 4; rt++)
#pragma unroll
        for (int t = 0; t < TPW; t++) {
            int nb = wave * TPW + t;
            int col = nb * 16 + lrow;
#pragma unroll
            for (int j = 0; j < 4; j++) {
                float vv = acc[rt][t][j];
                if (DORELU) vv = fmaxf(vv, 0.f);
                out[(long)(v0 + rt * 16 + lgrp * 4 + j) * NC + col] = vv;
            }
        }
}

// ---------------- launch ----------------

extern "C" void kernel_launch(void* const* d_in, const int* in_sizes, int n_in,
                              void* d_out, int out_size, void* d_ws, size_t ws_size,
                              hipStream_t stream) {
    const float* xa     = (const float*)d_in[0];
    const float* xp     = (const float*)d_in[1];
    const int*   src    = (const int*)d_in[2];
    const int*   dst    = (const int*)d_in[3];
    const int*   et     = (const int*)d_in[4];
    const float* Wpa    = (const float*)d_in[5];
    const float* bpa    = (const float*)d_in[6];
    const float* Wpb    = (const float*)d_in[7];
    const float* bpb    = (const float*)d_in[8];
    const float* basis0 = (const float*)d_in[9];
    const float* comp0  = (const float*)d_in[10];
    const float* basis1 = (const float*)d_in[11];
    const float* comp1  = (const float*)d_in[12];
    const float* root1  = (const float*)d_in[13];
    const float* basis2 = (const float*)d_in[14];
    const float* comp2  = (const float*)d_in[15];
    const float* root2  = (const float*)d_in[16];

    // d_out layout: final [N,64] | x_lat0 [N,128] | x_lat1 [N,128] | x_lat2 [N,128]
    float* out_final = (float*)d_out;
    float* x0 = out_final + (size_t)NNODES * OUTCH;
    float* x1 = x0 + (size_t)NNODES * HIDC;
    float* x2 = x1 + (size_t)NNODES * HIDC;

    // workspace (~9.56 MB)
    int* bins      = (int*)d_ws;            // 800000: counts -> starts
    int* binCur    = bins + SCAN_N;         // 800000: cursor -> ends
    int* gctr      = binCur + SCAN_N;       // 1 (+pad): global segment cursor
    int* srcSorted = gctr + 800;            // 600000
    short* whi0  = (short*)(srcSorted + NEDGE);  // 65536
    short* wlo0  = whi0 + 65536;
    short* whi1  = wlo0 + 65536;                 // 65536
    short* wlo1  = whi1 + 65536;
    short* whiR1 = wlo1 + 65536;                 // 16384
    short* wloR1 = whiR1 + 16384;
    short* whi2  = wloR1 + 16384;                // 32768
    short* wlo2  = whi2 + 32768;
    short* whiR2 = wlo2 + 32768;                 // 8192
    short* wloR2 = whiR2 + 8192;

    dim3 b256(256);
    int egrid = (NEDGE + 255) / 256;
    int nScanBlocks = (SCAN_N + 1023) / 1024;  // 782

    // ---- counting-sort of src ids by (relation, dst) ----
    hipMemsetAsync(bins, 0, (size_t)SCAN_N * sizeof(int), stream);
    hipMemsetAsync(gctr, 0, sizeof(int), stream);
    hipLaunchKernelGGL(count_kernel, dim3(egrid), b256, 0, stream, dst, et, bins);
    hipLaunchKernelGGL(scan_fused_kernel, dim3(nScanBlocks), b256, 0, stream,
                       bins, binCur, gctr);
    hipLaunchKernelGGL(scatter_kernel, dim3(egrid), b256, 0, stream,
                       src, dst, et, binCur, srcSorted);

    // ---- materialize relation+root weights as bf16 hi/lo MFMA fragments ----
    hipLaunchKernelGGL(fragify_kernel, dim3((188416 + 255) / 256), b256, 0, stream,
                       basis0, comp0, basis1, comp1, root1, basis2, comp2, root2,
                       whi0, wlo0, whi1, wlo1, whiR1, wloR1, whi2, wlo2, whiR2, wloR2);

    // ---- projections -> x_lat0 ----
    hipLaunchKernelGGL(gemm_kernel, dim3((NAUT + 63) / 64), b256, 0, stream,
                       xa, Wpa, bpa, x0, NAUT, 64);
    hipLaunchKernelGGL(gemm_kernel, dim3((NAUT + 63) / 64), b256, 0, stream,
                       xp, Wpb, bpb, x0 + (size_t)NAUT * HIDC, NAUT, 96);

    int cgrid = NNODES / 64;  // 3125, exact

    // conv0: x1 = relu(aggr(x0))            (no root)
    hipLaunchKernelGGL((conv_kernel<128, false, true>), dim3(cgrid), b256, 0, stream,
                       x0, whi0, wlo0, (const short*)nullptr, (const short*)nullptr,
                       bins, binCur, srcSorted, x1);
    // conv1: x2 = relu(x1 @ root1 + aggr(x1))
    hipLaunchKernelGGL((conv_kernel<128, true, true>), dim3(cgrid), b256, 0, stream,
                       x1, whi1, wlo1, whiR1, wloR1, bins, binCur, srcSorted, x2);
    // conv2: final = x2 @ root2 + aggr(x2)  (no relu)
    hipLaunchKernelGGL((conv_kernel<64, true, false>), dim3(cgrid), b256, 0, stream,
                       x2, whi2, wlo2, whiR2, wloR2, bins, binCur, srcSorted, out_final);
}